// Round 5
// baseline (7027.360 us; speedup 1.0000x reference)
//
#include <hip/hip_runtime.h>
#include <cstdint>
#include <cstddef>

#define B_    4
#define S_    1024
#define CNN_DIM 512
#define LLM_DIM 768
#define BR_DIM  1024
#define NH    16
#define SAUG  1027

typedef __attribute__((ext_vector_type(8))) short short8;
typedef __attribute__((ext_vector_type(4))) float f32x4;
typedef unsigned short u16;

__device__ __forceinline__ float bf2f(u16 h) {
    union { unsigned u; float f; } c; c.u = ((unsigned)h) << 16; return c.f;
}
__device__ __forceinline__ u16 f2bf(float f) {
    union { unsigned u; float f; } c; c.f = f;
    return (u16)((c.u + 0x7FFFu + ((c.u >> 16) & 1u)) >> 16);
}
__device__ __forceinline__ short f2bfS(float f) { return (short)f2bf(f); }

// ---------------- MFMA layout probe (verifies full A/B/D contract) ----------------
__global__ void probe_mfma(int* flag) {
    const int lane = threadIdx.x;
    const int mi = lane & 15, g = lane >> 4;
    short8 a, b;
#pragma unroll
    for (int j = 0; j < 8; j++) {
        int k = g * 8 + j;
        a[j] = f2bfS((float)(((mi * 5 + k * 3) % 7) - 3));
        b[j] = f2bfS((float)(((mi * 3 + k) % 5) - 2));
    }
    f32x4 acc = {0.f, 0.f, 0.f, 0.f};
    acc = __builtin_amdgcn_mfma_f32_16x16x32_bf16(a, b, acc, 0, 0, 0);
    bool okS = true, okT = true;
#pragma unroll
    for (int r = 0; r < 4; r++) {
        int rowS = g * 4 + r, colS = mi;
        float refS = 0.f, refT = 0.f;
        for (int k = 0; k < 32; k++) {
            refS += (float)(((rowS * 5 + k * 3) % 7) - 3) * (float)(((colS * 3 + k) % 5) - 2);
            refT += (float)(((colS * 5 + k * 3) % 7) - 3) * (float)(((rowS * 3 + k) % 5) - 2);
        }
        okS = okS && (acc[r] == refS);
        okT = okT && (acc[r] == refT);
    }
    unsigned long long bS = __ballot(okS), bT = __ballot(okT);
    if (lane == 0) *flag = (bS == ~0ULL) ? 0 : ((bT == ~0ULL) ? 1 : 2);
}

// ---------------- GEMM: C[M,N](bf16) = A[M,K] @ W[N,K]^T + bias (+resid) ----------------
// W, bias always f32 (read straight from d_in). A bf16 or f32. RESID: 0 none, 1 bf16, 2 f32.
template<bool A_F32, int RESID>
__global__ __launch_bounds__(256) void gemm_kernel(
    const void* __restrict__ Avp, const float* __restrict__ W,
    const float* __restrict__ bias, const void* __restrict__ residp,
    u16* __restrict__ C, int M, int N, int K, const int* __restrict__ flagp)
{
    const int mode = *flagp;
    const int lane = threadIdx.x & 63;
    const int wave = threadIdx.x >> 6;
    const int wm = wave & 1, wn = wave >> 1;
    const int m0 = blockIdx.y * 64 + wm * 32;
    const int n0 = blockIdx.x * 128 + wn * 64;

    if (mode < 2) {
        const int lr = lane & 15;
        const int ko = (lane >> 4) * 8;
        f32x4 acc[2][4] = {};

        int ar0 = m0 + lr;       if (ar0 > M - 1) ar0 = M - 1;
        int ar1 = m0 + 16 + lr;  if (ar1 > M - 1) ar1 = M - 1;
        const size_t aoff0 = (size_t)ar0 * K + ko;
        const size_t aoff1 = (size_t)ar1 * K + ko;

        for (int k0 = 0; k0 < K; k0 += 32) {
            short8 a0, a1;
            if (A_F32) {
                const float* A = (const float*)Avp;
                const float* p0 = A + aoff0 + k0;
                const float* p1 = A + aoff1 + k0;
                float4 x0 = *(const float4*)p0, x1 = *(const float4*)(p0 + 4);
                float4 y0 = *(const float4*)p1, y1 = *(const float4*)(p1 + 4);
                a0[0]=f2bfS(x0.x); a0[1]=f2bfS(x0.y); a0[2]=f2bfS(x0.z); a0[3]=f2bfS(x0.w);
                a0[4]=f2bfS(x1.x); a0[5]=f2bfS(x1.y); a0[6]=f2bfS(x1.z); a0[7]=f2bfS(x1.w);
                a1[0]=f2bfS(y0.x); a1[1]=f2bfS(y0.y); a1[2]=f2bfS(y0.z); a1[3]=f2bfS(y0.w);
                a1[4]=f2bfS(y1.x); a1[5]=f2bfS(y1.y); a1[6]=f2bfS(y1.z); a1[7]=f2bfS(y1.w);
            } else {
                const u16* A = (const u16*)Avp;
                a0 = *(const short8*)(A + aoff0 + k0);
                a1 = *(const short8*)(A + aoff1 + k0);
            }
#pragma unroll
            for (int ni = 0; ni < 4; ni++) {
                const float* wp = W + (size_t)(n0 + ni * 16 + lr) * K + ko + k0;
                float4 w0 = *(const float4*)wp, w1 = *(const float4*)(wp + 4);
                short8 b;
                b[0]=f2bfS(w0.x); b[1]=f2bfS(w0.y); b[2]=f2bfS(w0.z); b[3]=f2bfS(w0.w);
                b[4]=f2bfS(w1.x); b[5]=f2bfS(w1.y); b[6]=f2bfS(w1.z); b[7]=f2bfS(w1.w);
                acc[0][ni] = __builtin_amdgcn_mfma_f32_16x16x32_bf16(a0, b, acc[0][ni], 0, 0, 0);
                acc[1][ni] = __builtin_amdgcn_mfma_f32_16x16x32_bf16(a1, b, acc[1][ni], 0, 0, 0);
            }
        }

        const int r0 = (lane >> 4) * 4;
#pragma unroll
        for (int mi = 0; mi < 2; mi++) {
#pragma unroll
            for (int r = 0; r < 4; r++) {
                int lrow = mode ? lr : (r0 + r);
                int lcol = mode ? (r0 + r) : lr;
                int row = m0 + mi * 16 + lrow;
                if (row >= M) continue;
                size_t base = (size_t)row * N;
#pragma unroll
                for (int ni = 0; ni < 4; ni++) {
                    int col = n0 + ni * 16 + lcol;
                    float v = acc[mi][ni][r] + bias[col];
                    if (RESID == 1) v += bf2f(((const u16*)residp)[base + col]);
                    if (RESID == 2) v += ((const float*)residp)[base + col];
                    C[base + col] = f2bf(v);
                }
            }
        }
    } else {
        // scalar fallback: lane -> 1 row x 32 cols of the wave's 32x64 tile
        const int r = lane & 31, half = lane >> 5;
        const int row = m0 + r;
        const int cb = n0 + half * 32;
        if (row >= M) return;
        float acc[32];
#pragma unroll
        for (int c = 0; c < 32; c++) acc[c] = 0.f;
        for (int k = 0; k < K; k++) {
            float av = A_F32 ? ((const float*)Avp)[(size_t)row * K + k]
                             : bf2f(((const u16*)Avp)[(size_t)row * K + k]);
            av = bf2f(f2bf(av));
            for (int c = 0; c < 32; c++)
                acc[c] += av * bf2f(f2bf(W[(size_t)(cb + c) * K + k]));
        }
        size_t base = (size_t)row * N;
        for (int c = 0; c < 32; c++) {
            float v = acc[c] + bias[cb + c];
            if (RESID == 1) v += bf2f(((const u16*)residp)[base + cb + c]);
            if (RESID == 2) v += ((const float*)residp)[base + cb + c];
            C[base + cb + c] = f2bf(v);
        }
    }
}

// ---------------- attention: one wave per query row ----------------
template<int DH>
__global__ __launch_bounds__(256) void attn_kernel(
    const u16* __restrict__ Qb, const u16* __restrict__ Kb,
    const u16* __restrict__ Vb, u16* __restrict__ Ob,
    int Sk, int q_rs, int kv_rs, int o_rs,
    long long q_bs, long long kv_bs, long long o_bs, float scale)
{
    __shared__ float ps[4][1056];
    __shared__ float qs[4][DH];
    const int lane = threadIdx.x & 63;
    const int w = threadIdx.x >> 6;
    const int b = blockIdx.z, h = blockIdx.y;
    const int qr = blockIdx.x * 4 + w;
    const int hoff = h * DH;

    const u16* qrow = Qb + (size_t)b * q_bs + (size_t)qr * q_rs + hoff;
    if (lane < DH) qs[w][lane] = bf2f(qrow[lane]);
    __syncthreads();

    const u16* kbase = Kb + (size_t)b * kv_bs + hoff;
    float mloc = -3.0e38f;
    for (int kk = lane; kk < Sk; kk += 64) {
        const u16* kr = kbase + (size_t)kk * kv_rs;
        float dot = 0.f;
#pragma unroll
        for (int j0 = 0; j0 < DH; j0 += 8) {
            short8 kv8 = *(const short8*)(kr + j0);
#pragma unroll
            for (int u = 0; u < 8; u++) dot += qs[w][j0 + u] * bf2f((u16)kv8[u]);
        }
        float sc = dot * scale;
        ps[w][kk] = sc;
        mloc = fmaxf(mloc, sc);
    }
#pragma unroll
    for (int off = 32; off; off >>= 1) mloc = fmaxf(mloc, __shfl_xor(mloc, off));

    float ssum = 0.f;
    for (int kk = lane; kk < Sk; kk += 64) {
        float p = __expf(ps[w][kk] - mloc);
        ps[w][kk] = p;
        ssum += p;
    }
#pragma unroll
    for (int off = 32; off; off >>= 1) ssum += __shfl_xor(ssum, off);

    __syncthreads();

    if (lane < DH) {
        const u16* vbase = Vb + (size_t)b * kv_bs + hoff + lane;
        float accv = 0.f;
        for (int kk = 0; kk < Sk; kk++)
            accv += ps[w][kk] * bf2f(vbase[(size_t)kk * kv_rs]);
        Ob[(size_t)b * o_bs + (size_t)qr * o_rs + hoff + lane] = f2bf(accv / ssum);
    }
}

// ---------------- LayerNorm (bf16 input, optional GELU / bf16 residual) ----------------
// OUTF32: write float32 (for d_out, which holds the reference's f32 output dtype)
template<bool GELU, bool RESID, bool OUTF32>
__global__ __launch_bounds__(256) void ln_kernel(
    const u16* __restrict__ X, const u16* __restrict__ resid,
    const float* __restrict__ g, const float* __restrict__ be,
    void* __restrict__ out, int N, int rows_per_batch,
    long long resid_bs, int resid_rs, long long out_bs, int out_rs)
{
    __shared__ float buf[1024];
    __shared__ float red[2][4];
    __shared__ float stat[2];
    const int row = blockIdx.x;
    const int b = row / rows_per_batch, r = row % rows_per_batch;
    const int tid = threadIdx.x, lane = tid & 63, w = tid >> 6;
    const u16* xr = X + (size_t)row * N;
    const u16* rr = RESID ? (resid + (size_t)b * resid_bs + (size_t)r * resid_rs) : (const u16*)nullptr;

    float s = 0.f, s2 = 0.f;
    for (int i = tid; i < N; i += 256) {
        float x = bf2f(xr[i]);
        if (RESID) x += bf2f(rr[i]);
        if (GELU)  x = 0.5f * x * (1.f + erff(x * 0.70710678118654752f));
        buf[i] = x; s += x; s2 += x * x;
    }
#pragma unroll
    for (int off = 32; off; off >>= 1) { s += __shfl_xor(s, off); s2 += __shfl_xor(s2, off); }
    if (lane == 0) { red[0][w] = s; red[1][w] = s2; }
    __syncthreads();
    if (tid == 0) {
        float a = red[0][0] + red[0][1] + red[0][2] + red[0][3];
        float q = red[1][0] + red[1][1] + red[1][2] + red[1][3];
        float mean = a / N;
        float var = q / N - mean * mean;
        stat[0] = mean; stat[1] = rsqrtf(var + 1e-5f);
    }
    __syncthreads();
    const float mean = stat[0], rs = stat[1];
    const size_t obase = (size_t)b * out_bs + (size_t)r * out_rs;
    for (int i = tid; i < N; i += 256) {
        float v = (buf[i] - mean) * rs * g[i] + be[i];
        if (OUTF32) ((float*)out)[obase + i] = v;
        else        ((u16*)out)[obase + i] = f2bf(v);
    }
}

// ---------------- phys embedding rows (f32 src -> bf16) ----------------
__global__ __launch_bounds__(256) void fill_phys_kernel(
    const float* __restrict__ e, const float* __restrict__ m, const float* __restrict__ p,
    u16* __restrict__ augc, u16* __restrict__ augl)
{
    int i = blockIdx.x * 256 + threadIdx.x;
    if (i >= 3 * BR_DIM) return;
    int r = i / BR_DIM, j = i % BR_DIM;
    u16 v = f2bf((r == 0) ? e[j] : (r == 1) ? m[j] : p[j]);
#pragma unroll
    for (int b = 0; b < B_; b++) {
        size_t off = ((size_t)b * SAUG + S_ + r) * BR_DIM + j;
        augc[off] = v; augl[off] = v;
    }
}

template<bool A_F32, int RESID>
static void gemm(hipStream_t s, const void* A, const float* W, const float* bias,
                 const void* resid, u16* C, int M, int N, int K, const int* flag)
{
    dim3 grid(N / 128, (M + 63) / 64), block(256);
    gemm_kernel<A_F32, RESID><<<grid, block, 0, s>>>(A, W, bias, resid, C, M, N, K, flag);
}

extern "C" void kernel_launch(void* const* d_in, const int* in_sizes, int n_in,
                              void* d_out, int out_size, void* d_ws, size_t ws_size,
                              hipStream_t stream)
{
    auto F = [&](int i) { return (const float*)d_in[i]; };
    uint8_t* ws = (uint8_t*)d_ws;

    // ---- compact workspace layout (high-water ~50.6 MB) ----
    int* FLAG = (int*)(ws + 0);
    u16* QKV  = (u16*)(ws + 256);         // 12,582,912 B
    u16* ATT  = (u16*)(ws + 12583168);    // 4 MB
    u16* CNN1 = (u16*)(ws + 16777472);    // 4 MB
    u16* CNN2 = (u16*)(ws + 20971776);    // 4 MB
    u16* AUGC = (u16*)(ws + 25296896);    // 8,413,184 B
    u16* AUGL = (u16*)(ws + 33710080);    // 8,413,184 B
    u16* X8   = (u16*)(ws + 256);         // 8 MB scratch (QKV region, reused)
    u16* PQ1  = (u16*)(ws + 256);
    u16* PK1  = (u16*)(ws + 8413440);
    u16* PV1  = (u16*)(ws + 16826624);
    u16* OB1  = (u16*)(ws + 42123264);    // 8 MB
    u16* X8b  = (u16*)(ws + 256);
    u16* CATT = (u16*)(ws + 8413440);     // 8 MB
    u16* PK2  = (u16*)(ws + 16826624);
    u16* PV2  = (u16*)(ws + 42123264);
    u16* PQ2  = (u16*)(ws + 25296896);    // over dead AUGC
    u16* OB2  = (u16*)(ws + 256);
    u16* X8c  = (u16*)(ws + 16826624);
    u16* LATT = (u16*)(ws + 25296896);    // over dead PQ2
    u16* X6   = (u16*)(ws + 256);
    u16* X4   = (u16*)(ws + 256);
    float* outp = (float*)d_out;          // f32 output (reference output dtype)

    probe_mfma<<<1, 64, 0, stream>>>(FLAG);

    const int M4 = B_ * S_;
    const int MA = B_ * SAUG;
    const float sc32 = 0.17677669529663687f;
    const float sc64 = 0.125f;
    const long long bsQKV = (long long)S_ * 3 * CNN_DIM;
    const long long bsAUG = (long long)SAUG * BR_DIM;
    const long long bsO   = (long long)S_ * BR_DIM;
    dim3 agrid(S_ / 4, NH, B_), ablock(256);

    // ---- MHA 1 (spatial): A = f32 input, resid = f32 input ----
    gemm<true, 0>(stream, F(2), F(3), F(4), nullptr, QKV, M4, 3 * CNN_DIM, CNN_DIM, FLAG);
    attn_kernel<32><<<agrid, ablock, 0, stream>>>(QKV, QKV + CNN_DIM, QKV + 2 * CNN_DIM, ATT,
        S_, 3 * CNN_DIM, 3 * CNN_DIM, CNN_DIM, bsQKV, bsQKV, (long long)S_ * CNN_DIM, sc32);
    gemm<false, 2>(stream, ATT, F(5), F(6), F(2), CNN1, M4, CNN_DIM, CNN_DIM, FLAG);

    // ---- MHA 2 (temporal) ----
    gemm<false, 0>(stream, CNN1, F(7), F(8), nullptr, QKV, M4, 3 * CNN_DIM, CNN_DIM, FLAG);
    attn_kernel<32><<<agrid, ablock, 0, stream>>>(QKV, QKV + CNN_DIM, QKV + 2 * CNN_DIM, ATT,
        S_, 3 * CNN_DIM, 3 * CNN_DIM, CNN_DIM, bsQKV, bsQKV, (long long)S_ * CNN_DIM, sc32);
    gemm<false, 1>(stream, ATT, F(9), F(10), CNN1, CNN2, M4, CNN_DIM, CNN_DIM, FLAG);

    // ---- bridges to BR_DIM (Linear -> GELU -> LN) ----
    gemm<false, 0>(stream, CNN2, F(11), F(12), nullptr, X8, M4, BR_DIM, CNN_DIM, FLAG);
    ln_kernel<true, false, false><<<M4, 256, 0, stream>>>(X8, nullptr, F(13), F(14), AUGC,
        BR_DIM, S_, 0, 0, bsAUG, BR_DIM);
    gemm<true, 0>(stream, F(1), F(15), F(16), nullptr, X8, M4, BR_DIM, LLM_DIM, FLAG);
    ln_kernel<true, false, false><<<M4, 256, 0, stream>>>(X8, nullptr, F(17), F(18), AUGL,
        BR_DIM, S_, 0, 0, bsAUG, BR_DIM);
    fill_phys_kernel<<<12, 256, 0, stream>>>(F(27), F(28), F(29), AUGC, AUGL);

    // ---- phys attn 1: Q = proj(aug_cnn), K/V = proj(aug_llm); biases are softmax no-ops ----
    gemm<false, 0>(stream, AUGC, F(19), F(20), nullptr, PQ1, MA, BR_DIM, BR_DIM, FLAG);
    gemm<false, 0>(stream, AUGL, F(21), F(22), nullptr, PK1, MA, BR_DIM, BR_DIM, FLAG);
    gemm<false, 0>(stream, AUGL, F(23), F(24), nullptr, PV1, MA, BR_DIM, BR_DIM, FLAG);
    attn_kernel<64><<<agrid, ablock, 0, stream>>>(PQ1, PK1, PV1, OB1,
        SAUG, BR_DIM, BR_DIM, BR_DIM, bsAUG, bsAUG, bsO, sc64);
    gemm<false, 0>(stream, OB1, F(25), F(26), nullptr, X8b, M4, BR_DIM, BR_DIM, FLAG);
    ln_kernel<false, true, false><<<M4, 256, 0, stream>>>(X8b, AUGC, F(30), F(31), CATT,
        BR_DIM, S_, bsAUG, BR_DIM, bsO, BR_DIM);

    // ---- phys attn 2: K/V = proj(aug_cnn) first, then Q = proj(aug_llm) ----
    gemm<false, 0>(stream, AUGC, F(21), F(22), nullptr, PK2, MA, BR_DIM, BR_DIM, FLAG);
    gemm<false, 0>(stream, AUGC, F(23), F(24), nullptr, PV2, MA, BR_DIM, BR_DIM, FLAG);
    gemm<false, 0>(stream, AUGL, F(19), F(20), nullptr, PQ2, MA, BR_DIM, BR_DIM, FLAG);
    attn_kernel<64><<<agrid, ablock, 0, stream>>>(PQ2, PK2, PV2, OB2,
        SAUG, BR_DIM, BR_DIM, BR_DIM, bsAUG, bsAUG, bsO, sc64);
    gemm<false, 0>(stream, OB2, F(25), F(26), nullptr, X8c, M4, BR_DIM, BR_DIM, FLAG);
    ln_kernel<false, true, false><<<M4, 256, 0, stream>>>(X8c, AUGL, F(30), F(31), LATT,
        BR_DIM, S_, bsAUG, BR_DIM, bsO, BR_DIM);

    // ---- final bridges (write f32 to d_out) ----
    gemm<false, 0>(stream, CATT, F(32), F(33), nullptr, X6, M4, LLM_DIM, BR_DIM, FLAG);
    ln_kernel<true, false, true><<<M4, 256, 0, stream>>>(X6, nullptr, F(34), F(35),
        (void*)(outp + 2097152), LLM_DIM, S_, 0, 0, (long long)S_ * LLM_DIM, LLM_DIM);
    gemm<false, 0>(stream, LATT, F(36), F(37), nullptr, X4, M4, CNN_DIM, BR_DIM, FLAG);
    ln_kernel<true, false, true><<<M4, 256, 0, stream>>>(X4, nullptr, F(38), F(39),
        (void*)outp, CNN_DIM, S_, 0, 0, (long long)S_ * CNN_DIM, CNN_DIM);
}

// Round 6
// 1109.680 us; speedup vs baseline: 6.3328x; 6.3328x over previous
//
#include <hip/hip_runtime.h>
#include <cstdint>
#include <cstddef>

#define B_    4
#define S_    1024
#define CNN_DIM 512
#define LLM_DIM 768
#define BR_DIM  1024
#define NH    16
#define SAUG  1027

typedef __attribute__((ext_vector_type(8))) short short8;
typedef __attribute__((ext_vector_type(4))) float f32x4;
typedef __attribute__((ext_vector_type(4))) unsigned short us4;
typedef unsigned short u16;

__device__ __forceinline__ float bf2f(u16 h) {
    union { unsigned u; float f; } c; c.u = ((unsigned)h) << 16; return c.f;
}
__device__ __forceinline__ u16 f2bf(float f) {
    union { unsigned u; float f; } c; c.f = f;
    return (u16)((c.u + 0x7FFFu + ((c.u >> 16) & 1u)) >> 16);
}
__device__ __forceinline__ short f2bfS(float f) { return (short)f2bf(f); }

// ---------------- MFMA layout probe (for GEMM epilogue mode) ----------------
__global__ void probe_mfma(int* flag) {
    const int lane = threadIdx.x;
    const int mi = lane & 15, g = lane >> 4;
    short8 a, b;
#pragma unroll
    for (int j = 0; j < 8; j++) {
        int k = g * 8 + j;
        a[j] = f2bfS((float)(((mi * 5 + k * 3) % 7) - 3));
        b[j] = f2bfS((float)(((mi * 3 + k) % 5) - 2));
    }
    f32x4 acc = {0.f, 0.f, 0.f, 0.f};
    acc = __builtin_amdgcn_mfma_f32_16x16x32_bf16(a, b, acc, 0, 0, 0);
    bool okS = true, okT = true;
#pragma unroll
    for (int r = 0; r < 4; r++) {
        int rowS = g * 4 + r, colS = mi;
        float refS = 0.f, refT = 0.f;
        for (int k = 0; k < 32; k++) {
            refS += (float)(((rowS * 5 + k * 3) % 7) - 3) * (float)(((colS * 3 + k) % 5) - 2);
            refT += (float)(((colS * 5 + k * 3) % 7) - 3) * (float)(((rowS * 3 + k) % 5) - 2);
        }
        okS = okS && (acc[r] == refS);
        okT = okT && (acc[r] == refT);
    }
    unsigned long long bS = __ballot(okS), bT = __ballot(okT);
    if (lane == 0) *flag = (bS == ~0ULL) ? 0 : ((bT == ~0ULL) ? 1 : 2);
}

// ---------------- batched f32 -> bf16 conversion ----------------
#define NCONV 14
struct ConvArgs { const float* src[NCONV]; u16* dst[NCONV]; int cum[NCONV + 1]; };

__global__ __launch_bounds__(256) void convert_many(ConvArgs a, int total4) {
    int idx = blockIdx.x * 256 + threadIdx.x;
    if (idx >= total4) return;
    int seg = 0;
#pragma unroll
    for (int i = 1; i < NCONV; i++) if (a.cum[i] <= idx) seg = i;
    int j = idx - a.cum[seg];
    float4 v = ((const float4*)a.src[seg])[j];
    us4 o;
    o[0] = f2bf(v.x); o[1] = f2bf(v.y); o[2] = f2bf(v.z); o[3] = f2bf(v.w);
    ((us4*)a.dst[seg])[j] = o;
}

// ---------------- GEMM: C[M,N](bf16) = A[M,K]bf16 @ W[N,K]^T bf16 + bias(f32) (+resid) ----------------
// RESID: 0 none, 1 bf16, 2 f32
template<int RESID>
__global__ __launch_bounds__(256) void gemm_kernel(
    const u16* __restrict__ A, const u16* __restrict__ W,
    const float* __restrict__ bias, const void* __restrict__ residp,
    u16* __restrict__ C, int M, int N, int K, const int* __restrict__ flagp)
{
    const int mode = *flagp;
    const int lane = threadIdx.x & 63;
    const int wave = threadIdx.x >> 6;
    const int wm = wave & 1, wn = wave >> 1;
    const int m0 = blockIdx.y * 64 + wm * 32;
    const int n0 = blockIdx.x * 128 + wn * 64;

    if (mode < 2) {
        const int lr = lane & 15;
        const int ko = (lane >> 4) * 8;
        f32x4 acc[2][4] = {};

        int ar0 = m0 + lr;       if (ar0 > M - 1) ar0 = M - 1;
        int ar1 = m0 + 16 + lr;  if (ar1 > M - 1) ar1 = M - 1;
        const u16* ap0 = A + (size_t)ar0 * K + ko;
        const u16* ap1 = A + (size_t)ar1 * K + ko;
        const u16* bp  = W + (size_t)(n0 + lr) * K + ko;

        for (int k0 = 0; k0 < K; k0 += 32) {
            short8 a0 = *(const short8*)(ap0 + k0);
            short8 a1 = *(const short8*)(ap1 + k0);
#pragma unroll
            for (int ni = 0; ni < 4; ni++) {
                short8 b = *(const short8*)(bp + (size_t)ni * 16 * K + k0);
                acc[0][ni] = __builtin_amdgcn_mfma_f32_16x16x32_bf16(a0, b, acc[0][ni], 0, 0, 0);
                acc[1][ni] = __builtin_amdgcn_mfma_f32_16x16x32_bf16(a1, b, acc[1][ni], 0, 0, 0);
            }
        }

        const int r0 = (lane >> 4) * 4;
#pragma unroll
        for (int mi = 0; mi < 2; mi++) {
#pragma unroll
            for (int r = 0; r < 4; r++) {
                int lrow = mode ? lr : (r0 + r);
                int lcol = mode ? (r0 + r) : lr;
                int row = m0 + mi * 16 + lrow;
                if (row >= M) continue;
                size_t base = (size_t)row * N;
#pragma unroll
                for (int ni = 0; ni < 4; ni++) {
                    int col = n0 + ni * 16 + lcol;
                    float v = acc[mi][ni][r] + bias[col];
                    if (RESID == 1) v += bf2f(((const u16*)residp)[base + col]);
                    if (RESID == 2) v += ((const float*)residp)[base + col];
                    C[base + col] = f2bf(v);
                }
            }
        }
    } else {
        // scalar fallback (never expected; correctness insurance)
        const int r = lane & 31, half = lane >> 5;
        const int row = m0 + r;
        const int cb = n0 + half * 32;
        if (row >= M) return;
        float acc[32];
#pragma unroll
        for (int c = 0; c < 32; c++) acc[c] = 0.f;
        for (int k = 0; k < K; k++) {
            float av = bf2f(A[(size_t)row * K + k]);
            for (int c = 0; c < 32; c++)
                acc[c] += av * bf2f(W[(size_t)(cb + c) * K + k]);
        }
        size_t base = (size_t)row * N;
        for (int c = 0; c < 32; c++) {
            float v = acc[c] + bias[cb + c];
            if (RESID == 1) v += bf2f(((const u16*)residp)[base + cb + c]);
            if (RESID == 2) v += ((const float*)residp)[base + cb + c];
            C[base + cb + c] = f2bf(v);
        }
    }
}

// ---------------- MFMA flash attention ----------------
// Swapped form: S^T = mfma(A=K, B=Q^T)  -> lane (g,mi) holds S^T[key=4g+r][q=mi]
// softmax per q = per-lane + shfl_xor(16,32); O^T accumulated via
// mfma(A=V^T-from-LDS-columns, B=P^T-built-by-shfl).
// One wave owns 16 q rows; block = 4 waves = 64 q rows; K/V tiles (32 keys) in LDS.
template<int DH>
__global__ __launch_bounds__(256) void attn_mfma(
    const u16* __restrict__ Qb, const u16* __restrict__ Kb,
    const u16* __restrict__ Vb, u16* __restrict__ Ob,
    int Sk, int q_rs, int kv_rs, int o_rs,
    long long q_bs, long long kv_bs, long long o_bs, float scale)
{
    constexpr int KT = 32;
    constexpr int NDB = DH / 16;   // d-blocks
    constexpr int NCH = DH / 32;   // 32-dim chunks for QK
    constexpr int SEG = DH / 8;    // short8 segs per row
    constexpr int LDP = DH + 8;    // padded LDS row stride (x16B aligned: 72*2=144, 40*2=80)
    __shared__ __align__(16) u16 Kt[KT][LDP];
    __shared__ __align__(16) u16 Vs[KT][LDP];

    const int tid = threadIdx.x;
    const int lane = tid & 63;
    const int w = tid >> 6;
    const int mi = lane & 15, g = lane >> 4;
    const int b = blockIdx.z, h = blockIdx.y;
    const int hoff = h * DH;
    const int qw = blockIdx.x * 64 + w * 16;

    // Q^T B-frags, held in registers for the whole kernel
    short8 qfrag[NCH];
    {
        const u16* qsrc = Qb + (size_t)b * q_bs + (size_t)(qw + mi) * q_rs + hoff + g * 8;
#pragma unroll
        for (int c = 0; c < NCH; c++) qfrag[c] = *(const short8*)(qsrc + 32 * c);
    }

    f32x4 acc[NDB] = {};
    float m = -3.0e38f, l = 0.f;

    const int nt = (Sk + KT - 1) / KT;
    for (int t = 0; t < nt; t++) {
        __syncthreads();
        if (tid < KT * SEG) {
            int r = tid / SEG, sgi = tid % SEG;
            int key = t * KT + r;
            short8 kv = {0,0,0,0,0,0,0,0}, vv = {0,0,0,0,0,0,0,0};
            if (key < Sk) {
                const u16* kp = Kb + (size_t)b * kv_bs + (size_t)key * kv_rs + hoff + sgi * 8;
                const u16* vp = Vb + (size_t)b * kv_bs + (size_t)key * kv_rs + hoff + sgi * 8;
                kv = *(const short8*)kp;
                vv = *(const short8*)vp;
            }
            *(short8*)&Kt[r][sgi * 8] = kv;
            *(short8*)&Vs[r][sgi * 8] = vv;
        }
        __syncthreads();

        // ---- QK^T: two 16-key subtiles ----
        f32x4 sA = {0,0,0,0}, sB = {0,0,0,0};
#pragma unroll
        for (int c = 0; c < NCH; c++) {
            short8 ka = *(const short8*)&Kt[mi][g * 8 + 32 * c];
            short8 kb = *(const short8*)&Kt[16 + mi][g * 8 + 32 * c];
            sA = __builtin_amdgcn_mfma_f32_16x16x32_bf16(ka, qfrag[c], sA, 0, 0, 0);
            sB = __builtin_amdgcn_mfma_f32_16x16x32_bf16(kb, qfrag[c], sB, 0, 0, 0);
        }
        const int k0 = t * KT;
        float sa[4], sb[4];
#pragma unroll
        for (int r = 0; r < 4; r++) {
            sa[r] = (k0 + 4 * g + r < Sk)      ? sA[r] * scale : -3.0e38f;
            sb[r] = (k0 + 16 + 4 * g + r < Sk) ? sB[r] * scale : -3.0e38f;
        }
        float pm = sa[0];
#pragma unroll
        for (int r = 0; r < 4; r++) { pm = fmaxf(pm, sa[r]); pm = fmaxf(pm, sb[r]); }
        pm = fmaxf(pm, __shfl_xor(pm, 16));
        pm = fmaxf(pm, __shfl_xor(pm, 32));
        const float newm = fmaxf(m, pm);
        const float corr = __expf(m - newm);
        m = newm;
        l *= corr;
#pragma unroll
        for (int db = 0; db < NDB; db++) acc[db] *= corr;

        float pa[4], pb[4], psum = 0.f;
#pragma unroll
        for (int r = 0; r < 4; r++) {
            pa[r] = (sa[r] > -1.0e37f) ? __expf(sa[r] - newm) : 0.f;
            pb[r] = (sb[r] > -1.0e37f) ? __expf(sb[r] - newm) : 0.f;
            psum += pa[r] + pb[r];
        }
        psum += __shfl_xor(psum, 16);
        psum += __shfl_xor(psum, 32);
        l += psum;

        // ---- build P^T B-frag: pfrag[j] = P[q=mi][key=8g+j] ----
        const int src0 = ((2 * g) & 3) * 16 + mi;
        const int src1 = ((2 * g + 1) & 3) * 16 + mi;
        const bool useB = (g >= 2);
        short8 pfrag;
#pragma unroll
        for (int r = 0; r < 4; r++) {
            float vA0 = __shfl(pa[r], src0), vB0 = __shfl(pb[r], src0);
            float vA1 = __shfl(pa[r], src1), vB1 = __shfl(pb[r], src1);
            pfrag[r]     = f2bfS(useB ? vB0 : vA0);
            pfrag[4 + r] = f2bfS(useB ? vB1 : vA1);
        }

        // ---- PV: acc[db] += mfma(V^T[db], P^T) ----
#pragma unroll
        for (int db = 0; db < NDB; db++) {
            short8 vfrag;
#pragma unroll
            for (int j = 0; j < 8; j++) vfrag[j] = (short)Vs[g * 8 + j][db * 16 + mi];
            acc[db] = __builtin_amdgcn_mfma_f32_16x16x32_bf16(vfrag, pfrag, acc[db], 0, 0, 0);
        }
    }

    const float inv = 1.f / l;
    u16* obase = Ob + (size_t)b * o_bs + (size_t)(qw + mi) * o_rs + hoff;
#pragma unroll
    for (int db = 0; db < NDB; db++)
#pragma unroll
        for (int r = 0; r < 4; r++)
            obase[db * 16 + 4 * g + r] = f2bf(acc[db][r] * inv);
}

// ---------------- LayerNorm (bf16 input, optional GELU / residual, bf16|f32 out) ----------------
template<bool GELU, bool RESID, bool OUTF32>
__global__ __launch_bounds__(256) void ln_kernel(
    const u16* __restrict__ X, const u16* __restrict__ resid,
    const float* __restrict__ g, const float* __restrict__ be,
    void* __restrict__ out, int N, int rows_per_batch,
    long long resid_bs, int resid_rs, long long out_bs, int out_rs)
{
    __shared__ float buf[1024];
    __shared__ float red[2][4];
    __shared__ float stat[2];
    const int row = blockIdx.x;
    const int b = row / rows_per_batch, r = row % rows_per_batch;
    const int tid = threadIdx.x, lane = tid & 63, w = tid >> 6;
    const u16* xr = X + (size_t)row * N;
    const u16* rr = RESID ? (resid + (size_t)b * resid_bs + (size_t)r * resid_rs) : (const u16*)nullptr;

    float s = 0.f, s2 = 0.f;
    for (int i = tid; i < N; i += 256) {
        float x = bf2f(xr[i]);
        if (RESID) x += bf2f(rr[i]);
        if (GELU)  x = 0.5f * x * (1.f + erff(x * 0.70710678118654752f));
        buf[i] = x; s += x; s2 += x * x;
    }
#pragma unroll
    for (int off = 32; off; off >>= 1) { s += __shfl_xor(s, off); s2 += __shfl_xor(s2, off); }
    if (lane == 0) { red[0][w] = s; red[1][w] = s2; }
    __syncthreads();
    if (tid == 0) {
        float a = red[0][0] + red[0][1] + red[0][2] + red[0][3];
        float q = red[1][0] + red[1][1] + red[1][2] + red[1][3];
        float mean = a / N;
        float var = q / N - mean * mean;
        stat[0] = mean; stat[1] = rsqrtf(var + 1e-5f);
    }
    __syncthreads();
    const float mean = stat[0], rs = stat[1];
    const size_t obase = (size_t)b * out_bs + (size_t)r * out_rs;
    for (int i = tid; i < N; i += 256) {
        float v = (buf[i] - mean) * rs * g[i] + be[i];
        if (OUTF32) ((float*)out)[obase + i] = v;
        else        ((u16*)out)[obase + i] = f2bf(v);
    }
}

// ---------------- phys embedding rows (f32 src -> bf16) ----------------
__global__ __launch_bounds__(256) void fill_phys_kernel(
    const float* __restrict__ e, const float* __restrict__ m, const float* __restrict__ p,
    u16* __restrict__ augc, u16* __restrict__ augl)
{
    int i = blockIdx.x * 256 + threadIdx.x;
    if (i >= 3 * BR_DIM) return;
    int r = i / BR_DIM, j = i % BR_DIM;
    u16 v = f2bf((r == 0) ? e[j] : (r == 1) ? m[j] : p[j]);
#pragma unroll
    for (int b = 0; b < B_; b++) {
        size_t off = ((size_t)b * SAUG + S_ + r) * BR_DIM + j;
        augc[off] = v; augl[off] = v;
    }
}

template<int RESID>
static void gemm(hipStream_t s, const u16* A, const u16* W, const float* bias,
                 const void* resid, u16* C, int M, int N, int K, const int* flag)
{
    dim3 grid(N / 128, (M + 63) / 64), block(256);
    gemm_kernel<RESID><<<grid, block, 0, s>>>(A, W, bias, resid, C, M, N, K, flag);
}

extern "C" void kernel_launch(void* const* d_in, const int* in_sizes, int n_in,
                              void* d_out, int out_size, void* d_ws, size_t ws_size,
                              hipStream_t stream)
{
    auto F = [&](int i) { return (const float*)d_in[i]; };
    uint8_t* ws = (uint8_t*)d_ws;

    // ---- workspace layout (high-water ~95.5 MB; round-3 evidence: safe) ----
    int* FLAG     = (int*)(ws + 0);
    u16* W_SA_QKV = (u16*)(ws + 256);
    u16* W_SA_O   = (u16*)(ws + 1573120);
    u16* W_TA_QKV = (u16*)(ws + 2097408);
    u16* W_TA_O   = (u16*)(ws + 3670272);
    u16* W_C2B    = (u16*)(ws + 4194560);
    u16* W_L2B    = (u16*)(ws + 5243136);
    u16* W_PQ     = (u16*)(ws + 6816000);
    u16* W_PK     = (u16*)(ws + 8913152);
    u16* W_PV     = (u16*)(ws + 11010304);
    u16* W_PO     = (u16*)(ws + 13107456);
    u16* W_C2L    = (u16*)(ws + 15204608);
    u16* W_L2C    = (u16*)(ws + 16777472);
    u16* CNN_B    = (u16*)(ws + 17826048);   // 4x1024x512
    u16* LLM_B    = (u16*)(ws + 22020352);   // 4x1024x768
    u16* QKV      = (u16*)(ws + 28311808);   // 12.58 MB
    u16* ATT      = (u16*)(ws + 40894720);   // 4 MB
    u16* CNN1     = (u16*)(ws + 45089024);   // 4 MB
    u16* CNN2     = (u16*)(ws + 49283328);   // 4 MB
    u16* AUGC     = (u16*)(ws + 53477632);   // 8.41 MB
    u16* AUGL     = (u16*)(ws + 61890816);   // 8.41 MB
    u16* PQ       = (u16*)(ws + 70304000);   // 8.41 MB
    u16* PK       = (u16*)(ws + 78717184);
    u16* PV       = (u16*)(ws + 87130368);   // end 95,543,552
    u16* X8       = QKV;                     // 8 MB scratch (QKV dead)
    u16* OB       = QKV;                     // attn out, 8 MB
    u16* X8b      = (u16*)(ws + 36700416);   // 8 MB (QKV tail + ATT, dead)
    u16* CATT     = (u16*)(ws + 45089024);   // 8 MB (CNN1+CNN2, dead)
    u16* LATT     = (u16*)(ws + 53477632);   // 8 MB (AUGC after last read)
    u16* X6       = QKV;
    u16* X4       = QKV;
    float* outp   = (float*)d_out;

    probe_mfma<<<1, 64, 0, stream>>>(FLAG);

    // ---- convert weights + features to bf16 ----
    ConvArgs ca;
    const float* srcs[NCONV] = { F(1), F(2), F(3), F(5), F(7), F(9), F(11),
                                 F(15), F(19), F(21), F(23), F(25), F(32), F(36) };
    u16* dsts[NCONV] = { LLM_B, CNN_B, W_SA_QKV, W_SA_O, W_TA_QKV, W_TA_O, W_C2B,
                         W_L2B, W_PQ, W_PK, W_PV, W_PO, W_C2L, W_L2C };
    const int ns[NCONV] = { 3145728, 2097152, 786432, 262144, 786432, 262144, 524288,
                            786432, 1048576, 1048576, 1048576, 1048576, 786432, 524288 };
    int cum = 0;
    for (int i = 0; i < NCONV; i++) { ca.src[i] = srcs[i]; ca.dst[i] = dsts[i]; ca.cum[i] = cum; cum += ns[i] / 4; }
    ca.cum[NCONV] = cum;
    convert_many<<<(cum + 255) / 256, 256, 0, stream>>>(ca, cum);

    const int M4 = B_ * S_;
    const int MA = B_ * SAUG;
    const float sc32 = 0.17677669529663687f;
    const float sc64 = 0.125f;
    const long long bsQKV = (long long)S_ * 3 * CNN_DIM;
    const long long bsATT = (long long)S_ * CNN_DIM;
    const long long bsAUG = (long long)SAUG * BR_DIM;
    const long long bsO   = (long long)S_ * BR_DIM;
    dim3 agrid(S_ / 64, NH, B_), ablock(256);

    // ---- MHA 1 (spatial) ----
    gemm<0>(stream, CNN_B, W_SA_QKV, F(4), nullptr, QKV, M4, 3 * CNN_DIM, CNN_DIM, FLAG);
    attn_mfma<32><<<agrid, ablock, 0, stream>>>(QKV, QKV + CNN_DIM, QKV + 2 * CNN_DIM, ATT,
        S_, 3 * CNN_DIM, 3 * CNN_DIM, CNN_DIM, bsQKV, bsQKV, bsATT, sc32);
    gemm<2>(stream, ATT, W_SA_O, F(6), F(2), CNN1, M4, CNN_DIM, CNN_DIM, FLAG);

    // ---- MHA 2 (temporal) ----
    gemm<0>(stream, CNN1, W_TA_QKV, F(8), nullptr, QKV, M4, 3 * CNN_DIM, CNN_DIM, FLAG);
    attn_mfma<32><<<agrid, ablock, 0, stream>>>(QKV, QKV + CNN_DIM, QKV + 2 * CNN_DIM, ATT,
        S_, 3 * CNN_DIM, 3 * CNN_DIM, CNN_DIM, bsQKV, bsQKV, bsATT, sc32);
    gemm<1>(stream, ATT, W_TA_O, F(10), CNN1, CNN2, M4, CNN_DIM, CNN_DIM, FLAG);

    // ---- bridges to BR_DIM (Linear -> GELU -> LN) ----
    gemm<0>(stream, CNN2, W_C2B, F(12), nullptr, X8, M4, BR_DIM, CNN_DIM, FLAG);
    ln_kernel<true, false, false><<<M4, 256, 0, stream>>>(X8, nullptr, F(13), F(14), AUGC,
        BR_DIM, S_, 0, 0, bsAUG, BR_DIM);
    gemm<0>(stream, LLM_B, W_L2B, F(16), nullptr, X8, M4, BR_DIM, LLM_DIM, FLAG);
    ln_kernel<true, false, false><<<M4, 256, 0, stream>>>(X8, nullptr, F(17), F(18), AUGL,
        BR_DIM, S_, 0, 0, bsAUG, BR_DIM);
    fill_phys_kernel<<<12, 256, 0, stream>>>(F(27), F(28), F(29), AUGC, AUGL);

    // ---- phys attn 1: Q = proj(aug_cnn), K/V = proj(aug_llm); bias terms are softmax no-ops ----
    gemm<0>(stream, AUGC, W_PQ, F(20), nullptr, PQ, MA, BR_DIM, BR_DIM, FLAG);
    gemm<0>(stream, AUGL, W_PK, F(22), nullptr, PK, MA, BR_DIM, BR_DIM, FLAG);
    gemm<0>(stream, AUGL, W_PV, F(24), nullptr, PV, MA, BR_DIM, BR_DIM, FLAG);
    attn_mfma<64><<<agrid, ablock, 0, stream>>>(PQ, PK, PV, OB,
        SAUG, BR_DIM, BR_DIM, BR_DIM, bsAUG, bsAUG, bsO, sc64);
    gemm<0>(stream, OB, W_PO, F(26), nullptr, X8b, M4, BR_DIM, BR_DIM, FLAG);
    ln_kernel<false, true, false><<<M4, 256, 0, stream>>>(X8b, AUGC, F(30), F(31), CATT,
        BR_DIM, S_, bsAUG, BR_DIM, bsO, BR_DIM);

    // ---- phys attn 2: Q = proj(aug_llm), K/V = proj(aug_cnn) ----
    gemm<0>(stream, AUGC, W_PK, F(22), nullptr, PK, MA, BR_DIM, BR_DIM, FLAG);
    gemm<0>(stream, AUGC, W_PV, F(24), nullptr, PV, MA, BR_DIM, BR_DIM, FLAG);
    gemm<0>(stream, AUGL, W_PQ, F(20), nullptr, PQ, MA, BR_DIM, BR_DIM, FLAG);
    attn_mfma<64><<<agrid, ablock, 0, stream>>>(PQ, PK, PV, OB,
        SAUG, BR_DIM, BR_DIM, BR_DIM, bsAUG, bsAUG, bsO, sc64);
    gemm<0>(stream, OB, W_PO, F(26), nullptr, X8b, M4, BR_DIM, BR_DIM, FLAG);
    ln_kernel<false, true, false><<<M4, 256, 0, stream>>>(X8b, AUGL, F(30), F(31), LATT,
        BR_DIM, S_, bsAUG, BR_DIM, bsO, BR_DIM);

    // ---- final bridges (f32 to d_out) ----
    gemm<0>(stream, CATT, W_C2L, F(33), nullptr, X6, M4, LLM_DIM, BR_DIM, FLAG);
    ln_kernel<true, false, true><<<M4, 256, 0, stream>>>(X6, nullptr, F(34), F(35),
        (void*)(outp + 2097152), LLM_DIM, S_, 0, 0, (long long)S_ * LLM_DIM, LLM_DIM);
    gemm<0>(stream, LATT, W_L2C, F(37), nullptr, X4, M4, CNN_DIM, BR_DIM, FLAG);
    ln_kernel<true, false, true><<<M4, 256, 0, stream>>>(X4, nullptr, F(38), F(39),
        (void*)outp, CNN_DIM, S_, 0, 0, (long long)S_ * CNN_DIM, CNN_DIM);
}

// Round 7
// 598.067 us; speedup vs baseline: 11.7501x; 1.8554x over previous
//
#include <hip/hip_runtime.h>
#include <cstdint>
#include <cstddef>

#define B_    4
#define S_    1024
#define CNN_DIM 512
#define LLM_DIM 768
#define BR_DIM  1024
#define NH    16
#define SAUG  1027

typedef __attribute__((ext_vector_type(8))) short short8;
typedef __attribute__((ext_vector_type(4))) float f32x4;
typedef __attribute__((ext_vector_type(4))) unsigned short us4;
typedef unsigned short u16;
typedef unsigned int u32;

__device__ __forceinline__ float bf2f(u16 h) {
    union { u32 u; float f; } c; c.u = ((u32)h) << 16; return c.f;
}
__device__ __forceinline__ u16 f2bf(float f) {
    union { u32 u; float f; } c; c.f = f;
    return (u16)((c.u + 0x7FFFu + ((c.u >> 16) & 1u)) >> 16);
}
__device__ __forceinline__ short f2bfS(float f) { return (short)f2bf(f); }

#define GLLDS(gp, lp) __builtin_amdgcn_global_load_lds( \
    (const __attribute__((address_space(1))) void*)(gp), \
    (__attribute__((address_space(3))) void*)(lp), 16, 0, 0)

// ---------------- batched f32 -> bf16 conversion ----------------
#define NCONV 14
struct ConvArgs { const float* src[NCONV]; u16* dst[NCONV]; int cum[NCONV + 1]; };

__global__ __launch_bounds__(256) void convert_many(ConvArgs a, int total4) {
    int idx = blockIdx.x * 256 + threadIdx.x;
    if (idx >= total4) return;
    int seg = 0;
#pragma unroll
    for (int i = 1; i < NCONV; i++) if (a.cum[i] <= idx) seg = i;
    int j = idx - a.cum[seg];
    float4 v = ((const float4*)a.src[seg])[j];
    us4 o;
    o[0] = f2bf(v.x); o[1] = f2bf(v.y); o[2] = f2bf(v.z); o[3] = f2bf(v.w);
    ((us4*)a.dst[seg])[j] = o;
}

// ---------------- GEMM v2: LDS-staged, swizzled, double-buffered ----------------
// C[M,N](bf16) = A[M,K]bf16 @ W[N,K]^T bf16 + bias(f32) (+resid)
// BM=64 BN=128 BK=64; 256 thr / 4 waves (2x2); wave tile 32x64.
// st_16x32 swizzle: LDS[row][col16] holds GLOBAL[row][col16 ^ (row&7)] (rule 21:
// linear gload_lds dest + inverse-swizzled per-lane global source + swizzled read).
template<int RESID>   // 0 none, 1 bf16, 2 f32
__global__ __launch_bounds__(256) void gemm2_kernel(
    const u16* __restrict__ A, const u16* __restrict__ W,
    const float* __restrict__ bias, const void* __restrict__ residp,
    u16* __restrict__ C, int M, int N, int K)
{
    __shared__ u16 smA[2][64 * 64];
    __shared__ u16 smB[2][128 * 64];

    const int tid = threadIdx.x;
    const int lane = tid & 63;
    const int w = tid >> 6;
    const int wm = w & 1, wn = w >> 1;
    const int mi = lane & 15, g = lane >> 4;
    const int m0 = blockIdx.y * 64;
    const int n0 = blockIdx.x * 128;
    const int lrow = lane >> 3;   // row within 8-row chunk
    const int lcol = lane & 7;    // col16 block within 64-col row

    f32x4 acc[2][4] = {};
    const int nk = K >> 6;
    int cur = 0;

    auto stage = [&](int buf, int kt) {
        const int kbase = kt * 64;
#pragma unroll
        for (int i = 0; i < 6; i++) {
            int c = w * 6 + i;                 // 24 chunks of 1KB: 8 A + 16 B
            if (c < 8) {
                int row = c * 8 + lrow;
                int col16 = lcol ^ (row & 7);
                int grow = m0 + row; if (grow > M - 1) grow = M - 1;
                GLLDS(A + (size_t)grow * K + kbase + col16 * 8, &smA[buf][c * 512]);
            } else {
                int c8 = c - 8;
                int row = c8 * 8 + lrow;
                int col16 = lcol ^ (row & 7);
                GLLDS(W + (size_t)(n0 + row) * K + kbase + col16 * 8, &smB[buf][c8 * 512]);
            }
        }
    };

    stage(0, 0);
    __syncthreads();

    for (int kt = 0; kt < nk; ++kt) {
        if (kt + 1 < nk) stage(cur ^ 1, kt + 1);
#pragma unroll
        for (int h = 0; h < 2; h++) {
            short8 af[2], bf[4];
#pragma unroll
            for (int im = 0; im < 2; im++) {
                int row = wm * 32 + im * 16 + mi;
                af[im] = *(const short8*)&smA[cur][row * 64 + ((h * 4 + g) ^ (mi & 7)) * 8];
            }
#pragma unroll
            for (int in = 0; in < 4; in++) {
                int row = wn * 64 + in * 16 + mi;
                bf[in] = *(const short8*)&smB[cur][row * 64 + ((h * 4 + g) ^ (mi & 7)) * 8];
            }
#pragma unroll
            for (int im = 0; im < 2; im++)
#pragma unroll
                for (int in = 0; in < 4; in++)
                    acc[im][in] = __builtin_amdgcn_mfma_f32_16x16x32_bf16(af[im], bf[in], acc[im][in], 0, 0, 0);
        }
        __syncthreads();
        cur ^= 1;
    }

#pragma unroll
    for (int im = 0; im < 2; im++) {
#pragma unroll
        for (int r = 0; r < 4; r++) {
            int row = m0 + wm * 32 + im * 16 + g * 4 + r;
            if (row >= M) continue;
            size_t base = (size_t)row * N;
#pragma unroll
            for (int in = 0; in < 4; in++) {
                int col = n0 + wn * 64 + in * 16 + mi;
                float v = acc[im][in][r] + bias[col];
                if (RESID == 1) v += bf2f(((const u16*)residp)[base + col]);
                if (RESID == 2) v += ((const float*)residp)[base + col];
                C[base + col] = f2bf(v);
            }
        }
    }
}

// ---------------- MFMA flash attention v2 (transposed-V LDS) ----------------
// S^T = mfma(A=K, B=Q^T); softmax per-lane + shfl_xor(16,32);
// O^T += mfma(A=V^T read as ds_read_b128 from VT[d][key], B=P^T built by shfl).
template<int DH>
__global__ __launch_bounds__(256) void attn2(
    const u16* __restrict__ Q, const u16* __restrict__ Kb,
    const u16* __restrict__ Vb, u16* __restrict__ Ob,
    int Sk, int q_rs, int kv_rs, int o_rs,
    long long q_bs, long long kv_bs, long long o_bs, float scale)
{
    constexpr int KT = 32;
    constexpr int NDB = DH / 16;
    constexpr int NCH = DH / 32;
    constexpr int KLDP = DH + 8;
    __shared__ __align__(16) u16 Kt[KT][KLDP];
    __shared__ __align__(16) u16 VT[DH][40];   // VT[d][key], stride 40 (b128-aligned)

    const int tid = threadIdx.x;
    const int lane = tid & 63;
    const int w = tid >> 6;
    const int mi = lane & 15, g = lane >> 4;
    const int b = blockIdx.z, h = blockIdx.y;
    const int hoff = h * DH;
    const int qw = blockIdx.x * 64 + w * 16;

    short8 qfrag[NCH];
    {
        const u16* qs = Q + (size_t)b * q_bs + (size_t)(qw + mi) * q_rs + hoff + g * 8;
#pragma unroll
        for (int c = 0; c < NCH; c++) qfrag[c] = *(const short8*)(qs + 32 * c);
    }

    f32x4 acc[NDB] = {};
    float m = -3.0e38f, l = 0.f;
    const u16* kbb = Kb + (size_t)b * kv_bs + hoff;
    const u16* vbb = Vb + (size_t)b * kv_bs + hoff;

    const int nt = (Sk + KT - 1) / KT;
    for (int t = 0; t < nt; t++) {
        const int k0 = t * KT;
        const int rem = Sk - k0;
        __syncthreads();
        // K stage: row-major b128
        {
            int kr, seg; bool act = true;
            if (DH == 64) { kr = tid >> 3; seg = tid & 7; }
            else          { kr = tid >> 2; seg = tid & 3; act = (tid < 128); }
            if (act) {
                short8 kv = {0,0,0,0,0,0,0,0};
                if (kr < rem) kv = *(const short8*)(kbb + (size_t)(k0 + kr) * kv_rs + seg * 8);
                *(short8*)&Kt[kr][seg * 8] = kv;
            }
        }
        // V stage transposed: u32-pair writes VT[d][2kp..2kp+1]
        {
            int kp, seg; bool act = true;
            if (DH == 64) { kp = tid >> 4; seg = tid & 15; }
            else          { kp = (tid >> 3) & 15; seg = tid & 7; act = (tid >= 128); }
            if (act) {
                uint2 a = {0, 0}, b2 = {0, 0};
                if (2 * kp     < rem) a  = *(const uint2*)(vbb + (size_t)(k0 + 2 * kp)     * kv_rs + seg * 4);
                if (2 * kp + 1 < rem) b2 = *(const uint2*)(vbb + (size_t)(k0 + 2 * kp + 1) * kv_rs + seg * 4);
                u32* vt32 = (u32*)&VT[0][0];
                int d0 = seg * 4;
                vt32[(d0 + 0) * 20 + kp] = (a.x & 0xffffu) | (b2.x << 16);
                vt32[(d0 + 1) * 20 + kp] = (a.x >> 16)     | (b2.x & 0xffff0000u);
                vt32[(d0 + 2) * 20 + kp] = (a.y & 0xffffu) | (b2.y << 16);
                vt32[(d0 + 3) * 20 + kp] = (a.y >> 16)     | (b2.y & 0xffff0000u);
            }
        }
        __syncthreads();

        // ---- QK^T ----
        f32x4 sA = {0,0,0,0}, sB = {0,0,0,0};
#pragma unroll
        for (int c = 0; c < NCH; c++) {
            short8 ka = *(const short8*)&Kt[mi][g * 8 + 32 * c];
            short8 kb = *(const short8*)&Kt[16 + mi][g * 8 + 32 * c];
            sA = __builtin_amdgcn_mfma_f32_16x16x32_bf16(ka, qfrag[c], sA, 0, 0, 0);
            sB = __builtin_amdgcn_mfma_f32_16x16x32_bf16(kb, qfrag[c], sB, 0, 0, 0);
        }
        float sa[4], sb[4];
        if (rem >= KT) {
#pragma unroll
            for (int r = 0; r < 4; r++) { sa[r] = sA[r] * scale; sb[r] = sB[r] * scale; }
        } else {
#pragma unroll
            for (int r = 0; r < 4; r++) {
                sa[r] = (4 * g + r < rem)      ? sA[r] * scale : -3.0e38f;
                sb[r] = (16 + 4 * g + r < rem) ? sB[r] * scale : -3.0e38f;
            }
        }
        float pm = sa[0];
#pragma unroll
        for (int r = 0; r < 4; r++) { pm = fmaxf(pm, sa[r]); pm = fmaxf(pm, sb[r]); }
        pm = fmaxf(pm, __shfl_xor(pm, 16));
        pm = fmaxf(pm, __shfl_xor(pm, 32));
        if (__any(pm > m)) {                      // defer-rescale (exact: corr==1 otherwise)
            float newm = fmaxf(m, pm);
            float corr = __expf(m - newm);
            m = newm;
            l *= corr;
#pragma unroll
            for (int db = 0; db < NDB; db++) acc[db] *= corr;
        }

        float pa[4], pb[4], ps = 0.f;
#pragma unroll
        for (int r = 0; r < 4; r++) {
            pa[r] = __expf(sa[r] - m);            // masked lanes: exp(-inf)=0
            pb[r] = __expf(sb[r] - m);
            ps += pa[r] + pb[r];
        }
        ps += __shfl_xor(ps, 16);
        ps += __shfl_xor(ps, 32);
        l += ps;

        // ---- P^T B-frag via shfl: pfrag[j] = P[q=mi][key=8g+j] ----
        const int src0 = ((2 * g) & 3) * 16 + mi;
        const int src1 = ((2 * g + 1) & 3) * 16 + mi;
        const bool useB = (g >= 2);
        short8 pfrag;
#pragma unroll
        for (int r = 0; r < 4; r++) {
            float vA0 = __shfl(pa[r], src0), vB0 = __shfl(pb[r], src0);
            float vA1 = __shfl(pa[r], src1), vB1 = __shfl(pb[r], src1);
            pfrag[r]     = f2bfS(useB ? vB0 : vA0);
            pfrag[4 + r] = f2bfS(useB ? vB1 : vA1);
        }

        // ---- PV: one b128 per d-block ----
#pragma unroll
        for (int db = 0; db < NDB; db++) {
            short8 vf = *(const short8*)&VT[db * 16 + mi][g * 8];
            acc[db] = __builtin_amdgcn_mfma_f32_16x16x32_bf16(vf, pfrag, acc[db], 0, 0, 0);
        }
    }

    const float inv = 1.f / l;
    u16* obase = Ob + (size_t)b * o_bs + (size_t)(qw + mi) * o_rs + hoff;
#pragma unroll
    for (int db = 0; db < NDB; db++)
#pragma unroll
        for (int r = 0; r < 4; r++)
            obase[db * 16 + 4 * g + r] = f2bf(acc[db][r] * inv);
}

// ---------------- LayerNorm (vectorized; optional GELU / bf16 residual; bf16|f32 out) ----------------
template<bool GELU, bool RESID, bool OUTF32>
__global__ __launch_bounds__(256) void ln_kernel(
    const u16* __restrict__ X, const u16* __restrict__ resid,
    const float* __restrict__ gg, const float* __restrict__ be,
    void* __restrict__ out, int N, int rows_per_batch,
    long long resid_bs, int resid_rs, long long out_bs, int out_rs)
{
    __shared__ float buf[1024];
    __shared__ float red[2][4];
    __shared__ float stat[2];
    const int row = blockIdx.x;
    const int b = row / rows_per_batch, r = row % rows_per_batch;
    const int tid = threadIdx.x, lane = tid & 63, w = tid >> 6;
    const u16* xr = X + (size_t)row * N;
    const u16* rr = RESID ? (resid + (size_t)b * resid_bs + (size_t)r * resid_rs) : (const u16*)nullptr;

    float s = 0.f, s2 = 0.f;
    for (int i0 = tid * 4; i0 < N; i0 += 1024) {
        us4 xv = *(const us4*)(xr + i0);
        us4 rv = {0,0,0,0};
        if (RESID) rv = *(const us4*)(rr + i0);
        float4 xb;
        float* xp = &xb.x;
#pragma unroll
        for (int u = 0; u < 4; u++) {
            float x = bf2f(xv[u]);
            if (RESID) x += bf2f(rv[u]);
            if (GELU)  x = 0.5f * x * (1.f + erff(x * 0.70710678118654752f));
            xp[u] = x; s += x; s2 += x * x;
        }
        *(float4*)&buf[i0] = xb;
    }
#pragma unroll
    for (int off = 32; off; off >>= 1) { s += __shfl_xor(s, off); s2 += __shfl_xor(s2, off); }
    if (lane == 0) { red[0][w] = s; red[1][w] = s2; }
    __syncthreads();
    if (tid == 0) {
        float a = red[0][0] + red[0][1] + red[0][2] + red[0][3];
        float q = red[1][0] + red[1][1] + red[1][2] + red[1][3];
        float mean = a / N;
        float var = q / N - mean * mean;
        stat[0] = mean; stat[1] = rsqrtf(var + 1e-5f);
    }
    __syncthreads();
    const float mean = stat[0], rs = stat[1];
    const size_t obase = (size_t)b * out_bs + (size_t)r * out_rs;
    for (int i0 = tid * 4; i0 < N; i0 += 1024) {
        if (OUTF32) {
            float4 o;
            o.x = (buf[i0+0] - mean) * rs * gg[i0+0] + be[i0+0];
            o.y = (buf[i0+1] - mean) * rs * gg[i0+1] + be[i0+1];
            o.z = (buf[i0+2] - mean) * rs * gg[i0+2] + be[i0+2];
            o.w = (buf[i0+3] - mean) * rs * gg[i0+3] + be[i0+3];
            *(float4*)((float*)out + obase + i0) = o;
        } else {
            us4 o;
#pragma unroll
            for (int u = 0; u < 4; u++)
                o[u] = f2bf((buf[i0+u] - mean) * rs * gg[i0+u] + be[i0+u]);
            *(us4*)((u16*)out + obase + i0) = o;
        }
    }
}

// ---------------- phys embedding rows (f32 src -> bf16) ----------------
__global__ __launch_bounds__(256) void fill_phys_kernel(
    const float* __restrict__ e, const float* __restrict__ m, const float* __restrict__ p,
    u16* __restrict__ augc, u16* __restrict__ augl)
{
    int i = blockIdx.x * 256 + threadIdx.x;
    if (i >= 3 * BR_DIM) return;
    int r = i / BR_DIM, j = i % BR_DIM;
    u16 v = f2bf((r == 0) ? e[j] : (r == 1) ? m[j] : p[j]);
#pragma unroll
    for (int b = 0; b < B_; b++) {
        size_t off = ((size_t)b * SAUG + S_ + r) * BR_DIM + j;
        augc[off] = v; augl[off] = v;
    }
}

template<int RESID>
static void gemm(hipStream_t s, const u16* A, const u16* W, const float* bias,
                 const void* resid, u16* C, int M, int N, int K)
{
    dim3 grid(N / 128, (M + 63) / 64), block(256);
    gemm2_kernel<RESID><<<grid, block, 0, s>>>(A, W, bias, resid, C, M, N, K);
}

extern "C" void kernel_launch(void* const* d_in, const int* in_sizes, int n_in,
                              void* d_out, int out_size, void* d_ws, size_t ws_size,
                              hipStream_t stream)
{
    auto F = [&](int i) { return (const float*)d_in[i]; };
    uint8_t* ws = (uint8_t*)d_ws;

    // ---- workspace layout (identical to round 6; proven ≤95.5 MB) ----
    u16* W_SA_QKV = (u16*)(ws + 256);
    u16* W_SA_O   = (u16*)(ws + 1573120);
    u16* W_TA_QKV = (u16*)(ws + 2097408);
    u16* W_TA_O   = (u16*)(ws + 3670272);
    u16* W_C2B    = (u16*)(ws + 4194560);
    u16* W_L2B    = (u16*)(ws + 5243136);
    u16* W_PQ     = (u16*)(ws + 6816000);
    u16* W_PK     = (u16*)(ws + 8913152);
    u16* W_PV     = (u16*)(ws + 11010304);
    u16* W_PO     = (u16*)(ws + 13107456);
    u16* W_C2L    = (u16*)(ws + 15204608);
    u16* W_L2C    = (u16*)(ws + 16777472);
    u16* CNN_B    = (u16*)(ws + 17826048);
    u16* LLM_B    = (u16*)(ws + 22020352);
    u16* QKV      = (u16*)(ws + 28311808);
    u16* ATT      = (u16*)(ws + 40894720);
    u16* CNN1     = (u16*)(ws + 45089024);
    u16* CNN2     = (u16*)(ws + 49283328);
    u16* AUGC     = (u16*)(ws + 53477632);
    u16* AUGL     = (u16*)(ws + 61890816);
    u16* PQ       = (u16*)(ws + 70304000);
    u16* PK       = (u16*)(ws + 78717184);
    u16* PV       = (u16*)(ws + 87130368);
    u16* X8       = QKV;
    u16* OB       = QKV;
    u16* X8b      = (u16*)(ws + 36700416);
    u16* CATT     = (u16*)(ws + 45089024);
    u16* LATT     = (u16*)(ws + 53477632);
    u16* X6       = QKV;
    u16* X4       = QKV;
    float* outp   = (float*)d_out;

    // ---- convert weights + features to bf16 ----
    ConvArgs ca;
    const float* srcs[NCONV] = { F(1), F(2), F(3), F(5), F(7), F(9), F(11),
                                 F(15), F(19), F(21), F(23), F(25), F(32), F(36) };
    u16* dsts[NCONV] = { LLM_B, CNN_B, W_SA_QKV, W_SA_O, W_TA_QKV, W_TA_O, W_C2B,
                         W_L2B, W_PQ, W_PK, W_PV, W_PO, W_C2L, W_L2C };
    const int ns[NCONV] = { 3145728, 2097152, 786432, 262144, 786432, 262144, 524288,
                            786432, 1048576, 1048576, 1048576, 1048576, 786432, 524288 };
    int cum = 0;
    for (int i = 0; i < NCONV; i++) { ca.src[i] = srcs[i]; ca.dst[i] = dsts[i]; ca.cum[i] = cum; cum += ns[i] / 4; }
    ca.cum[NCONV] = cum;
    convert_many<<<(cum + 255) / 256, 256, 0, stream>>>(ca, cum);

    const int M4 = B_ * S_;
    const int MA = B_ * SAUG;
    const float sc32 = 0.17677669529663687f;
    const float sc64 = 0.125f;
    const long long bsQKV = (long long)S_ * 3 * CNN_DIM;
    const long long bsATT = (long long)S_ * CNN_DIM;
    const long long bsAUG = (long long)SAUG * BR_DIM;
    const long long bsO   = (long long)S_ * BR_DIM;
    dim3 agrid(S_ / 64, NH, B_), ablock(256);

    // ---- MHA 1 (spatial) ----
    gemm<0>(stream, CNN_B, W_SA_QKV, F(4), nullptr, QKV, M4, 3 * CNN_DIM, CNN_DIM);
    attn2<32><<<agrid, ablock, 0, stream>>>(QKV, QKV + CNN_DIM, QKV + 2 * CNN_DIM, ATT,
        S_, 3 * CNN_DIM, 3 * CNN_DIM, CNN_DIM, bsQKV, bsQKV, bsATT, sc32);
    gemm<2>(stream, ATT, W_SA_O, F(6), F(2), CNN1, M4, CNN_DIM, CNN_DIM);

    // ---- MHA 2 (temporal) ----
    gemm<0>(stream, CNN1, W_TA_QKV, F(8), nullptr, QKV, M4, 3 * CNN_DIM, CNN_DIM);
    attn2<32><<<agrid, ablock, 0, stream>>>(QKV, QKV + CNN_DIM, QKV + 2 * CNN_DIM, ATT,
        S_, 3 * CNN_DIM, 3 * CNN_DIM, CNN_DIM, bsQKV, bsQKV, bsATT, sc32);
    gemm<1>(stream, ATT, W_TA_O, F(10), CNN1, CNN2, M4, CNN_DIM, CNN_DIM);

    // ---- bridges to BR_DIM (Linear -> GELU -> LN) ----
    gemm<0>(stream, CNN2, W_C2B, F(12), nullptr, X8, M4, BR_DIM, CNN_DIM);
    ln_kernel<true, false, false><<<M4, 256, 0, stream>>>(X8, nullptr, F(13), F(14), AUGC,
        BR_DIM, S_, 0, 0, bsAUG, BR_DIM);
    gemm<0>(stream, LLM_B, W_L2B, F(16), nullptr, X8, M4, BR_DIM, LLM_DIM);
    ln_kernel<true, false, false><<<M4, 256, 0, stream>>>(X8, nullptr, F(17), F(18), AUGL,
        BR_DIM, S_, 0, 0, bsAUG, BR_DIM);
    fill_phys_kernel<<<12, 256, 0, stream>>>(F(27), F(28), F(29), AUGC, AUGL);

    // ---- phys attn 1: Q = proj(aug_cnn), K/V = proj(aug_llm) ----
    gemm<0>(stream, AUGC, W_PQ, F(20), nullptr, PQ, MA, BR_DIM, BR_DIM);
    gemm<0>(stream, AUGL, W_PK, F(22), nullptr, PK, MA, BR_DIM, BR_DIM);
    gemm<0>(stream, AUGL, W_PV, F(24), nullptr, PV, MA, BR_DIM, BR_DIM);
    attn2<64><<<agrid, ablock, 0, stream>>>(PQ, PK, PV, OB,
        SAUG, BR_DIM, BR_DIM, BR_DIM, bsAUG, bsAUG, bsO, sc64);
    gemm<0>(stream, OB, W_PO, F(26), nullptr, X8b, M4, BR_DIM, BR_DIM);
    ln_kernel<false, true, false><<<M4, 256, 0, stream>>>(X8b, AUGC, F(30), F(31), CATT,
        BR_DIM, S_, bsAUG, BR_DIM, bsO, BR_DIM);

    // ---- phys attn 2: Q = proj(aug_llm), K/V = proj(aug_cnn) ----
    gemm<0>(stream, AUGC, W_PK, F(22), nullptr, PK, MA, BR_DIM, BR_DIM);
    gemm<0>(stream, AUGC, W_PV, F(24), nullptr, PV, MA, BR_DIM, BR_DIM);
    gemm<0>(stream, AUGL, W_PQ, F(20), nullptr, PQ, MA, BR_DIM, BR_DIM);
    attn2<64><<<agrid, ablock, 0, stream>>>(PQ, PK, PV, OB,
        SAUG, BR_DIM, BR_DIM, BR_DIM, bsAUG, bsAUG, bsO, sc64);
    gemm<0>(stream, OB, W_PO, F(26), nullptr, X8b, M4, BR_DIM, BR_DIM);
    ln_kernel<false, true, false><<<M4, 256, 0, stream>>>(X8b, AUGL, F(30), F(31), LATT,
        BR_DIM, S_, bsAUG, BR_DIM, bsO, BR_DIM);

    // ---- final bridges (f32 to d_out) ----
    gemm<0>(stream, CATT, W_C2L, F(33), nullptr, X6, M4, LLM_DIM, BR_DIM);
    ln_kernel<true, false, true><<<M4, 256, 0, stream>>>(X6, nullptr, F(34), F(35),
        (void*)(outp + 2097152), LLM_DIM, S_, 0, 0, (long long)S_ * LLM_DIM, LLM_DIM);
    gemm<0>(stream, LATT, W_L2C, F(37), nullptr, X4, M4, CNN_DIM, BR_DIM);
    ln_kernel<true, false, true><<<M4, 256, 0, stream>>>(X4, nullptr, F(38), F(39),
        (void*)outp, CNN_DIM, S_, 0, 0, (long long)S_ * CNN_DIM, CNN_DIM);
}